// Round 8
// baseline (448.249 us; speedup 1.0000x reference)
//
#include <hip/hip_runtime.h>
#include <math.h>

#define Bb 32
#define Nn 4096
#define Cc 256
#define Mm 7
#define Dd 128
#define Hh 256
#define ITERS 3
#define EPS 1e-6f
#define LN_EPS 1e-5f
#define SCALE 0.08838834764831845f

typedef __attribute__((ext_vector_type(8))) short bf16x8;
typedef __attribute__((ext_vector_type(4))) float f32x4;

__device__ inline ushort f2bf(float f) {
  uint u = __builtin_bit_cast(uint, f);
  u += 0x7FFF + ((u >> 16) & 1);          // round-to-nearest-even
  return (ushort)(u >> 16);
}
__device__ inline float bf2f(ushort h) {
  uint u = ((uint)h) << 16;
  return __builtin_bit_cast(float, u);
}
__device__ inline uint pkbf(float a, float b) {
  return (uint)f2bf(a) | ((uint)f2bf(b) << 16);
}

// ---------------------------------------------------------------------------
// Prep: Wp[j][c] = bf16( ln_in_w[c] * Wkv[j][c] )   (j<128 -> Wk, else Wv)
//       Tj[j] = sum_c lw[c]*W[j][c], Uj[j] = sum_c lb[c]*W[j][c]   (fp32)
// ---------------------------------------------------------------------------
__global__ __launch_bounds__(256) void prep_w2t(
    const float* __restrict__ Wk, const float* __restrict__ Wv,
    const float* __restrict__ lw, const float* __restrict__ lb,
    ushort* __restrict__ Wp, float* __restrict__ Tj, float* __restrict__ Uj) {
  int j = blockIdx.x;     // 0..255 output channel
  int c = threadIdx.x;    // 0..255 input channel
  float wv = (j < Dd) ? Wk[j * Cc + c] : Wv[(j - Dd) * Cc + c];
  float lwc = lw[c], lbc = lb[c];
  float a = lwc * wv, u = lbc * wv;
  Wp[j * 256 + c] = f2bf(a);
  __shared__ float ra[4], ru[4];
  for (int s = 1; s < 64; s <<= 1) {
    a += __shfl_xor(a, s, 64);
    u += __shfl_xor(u, s, 64);
  }
  int lane = c & 63, w = c >> 6;
  if (lane == 0) { ra[w] = a; ru[w] = u; }
  __syncthreads();
  if (c == 0) {
    Tj[j] = ra[0] + ra[1] + ra[2] + ra[3];
    Uj[j] = ru[0] + ru[1] + ru[2] + ru[3];
  }
}

// ---------------------------------------------------------------------------
// Prep: transposes of Wq, gru_wi, gru_wh, mlp_w1, mlp_w2 (fp32, coalesced)
// ---------------------------------------------------------------------------
__global__ __launch_bounds__(256) void prep_trans(
    const float* __restrict__ Wq, const float* __restrict__ wi,
    const float* __restrict__ wh, const float* __restrict__ w1,
    const float* __restrict__ w2, float* __restrict__ WqT,
    float* __restrict__ wiT, float* __restrict__ whT,
    float* __restrict__ w1T, float* __restrict__ w2T) {
  int i = blockIdx.x * 256 + threadIdx.x;
  if (i < 16384) {                        // WqT[dd][d] = Wq[d][dd]
    int dd = i >> 7, d = i & 127;
    WqT[i] = Wq[d * 128 + dd];
  } else if (i < 65536) {                 // wiT[dd][j] = wi[j][dd]
    int i2 = i - 16384;
    int dd = i2 / 384, j = i2 % 384;
    wiT[i2] = wi[j * 128 + dd];
  } else if (i < 114688) {                // whT
    int i2 = i - 65536;
    int dd = i2 / 384, j = i2 % 384;
    whT[i2] = wh[j * 128 + dd];
  } else if (i < 147456) {                // w1T[dd][j] = w1[j][dd]
    int i2 = i - 114688;
    int dd = i2 >> 8, j = i2 & 255;
    w1T[i2] = w1[j * 128 + dd];
  } else if (i < 180224) {                // w2T[j][d] = w2[d][j]
    int i2 = i - 147456;
    int j = i2 >> 7, d = i2 & 127;
    w2T[i2] = w2[d * 256 + j];
  }
}

// ---------------------------------------------------------------------------
// q for iteration 0 + slots init + zero num/den. Block = (b*7+m), 128 thr.
// ---------------------------------------------------------------------------
__global__ __launch_bounds__(128) void q_prep0(
    const float* __restrict__ slots_mu, float* __restrict__ slots,
    const float* __restrict__ lsw, const float* __restrict__ lsb,
    const float* __restrict__ WqT, float* __restrict__ qs_g,
    float* __restrict__ num_g, float* __restrict__ den_g) {
  int row = blockIdx.x;
  int t = threadIdx.x;
  __shared__ float ys[128];
  __shared__ float red[4];
  float v = slots_mu[row * 128 + t];
  slots[row * 128 + t] = v;
  float sv = v, sq = v * v;
  for (int s = 1; s < 64; s <<= 1) {
    sv += __shfl_xor(sv, s, 64);
    sq += __shfl_xor(sq, s, 64);
  }
  if ((t & 63) == 0) {
    red[(t >> 6) * 2] = sv;
    red[(t >> 6) * 2 + 1] = sq;
  }
  __syncthreads();
  float tot = red[0] + red[2], totq = red[1] + red[3];
  float mean = tot * (1.f / 128.f);
  float var = totq * (1.f / 128.f) - mean * mean;
  ys[t] = (v - mean) * rsqrtf(var + LN_EPS) * lsw[t] + lsb[t];
  __syncthreads();
  float q = 0.f;
  for (int dd = 0; dd < 128; dd++) q += ys[dd] * WqT[dd * 128 + t];
  qs_g[row * 128 + t] = q;
  num_g[row * 128 + t] = 0.f;
  if (t == 0) den_g[row] = 0.f;
}

// ---------------------------------------------------------------------------
// KV projection, bf16 MFMA: out[row][j] = rstd*(x.W'_j - mean*Tj) + Uj
// 131072 x 256(K) x 256(N), BOTH k and v per block (x read once).
// 512 threads = 8 waves, wave grid 2x4, each 64x64 output.
// ---------------------------------------------------------------------------
__global__ __launch_bounds__(512) void kv_gemm_mfma(
    const float* __restrict__ x, const ushort* __restrict__ Wp,
    const float* __restrict__ Tj, const float* __restrict__ Uj,
    ushort* __restrict__ kg, ushort* __restrict__ vg) {
  __shared__ ushort As[128][40];   // [row][k] bf16, 80B stride (2-way, free)
  __shared__ ushort Bs[256][40];   // [col][k] bf16
  __shared__ float mean_s[128], rstd_s[128];
  int tid = threadIdx.x;
  int lane = tid & 63, w = tid >> 6;      // 8 waves
  int wr = w >> 2, wc = w & 3;            // 2x4 wave grid
  int cl = lane & 15, kq = lane >> 4;
  int row0 = blockIdx.x * 128;

  int ar = tid >> 2;                      // A staging: row 0..127
  int ah = (tid & 3) * 8;                 // 8 floats per thread
  int bc = tid >> 1;                      // B staging: col 0..255
  int bh = (tid & 1) * 16;                // 16 bf16 per thread
  const float*  xsrc = x  + (size_t)(row0 + ar) * 256 + ah;
  const ushort* wsrc = Wp + (size_t)bc * 256 + bh;

  float s_sum = 0.f, s_sq = 0.f;
  f32x4 acc[4][4] = {};

  for (int k0 = 0; k0 < 256; k0 += 32) {
    float4 xa = *(const float4*)(xsrc + k0);
    float4 xb = *(const float4*)(xsrc + k0 + 4);
    s_sum += xa.x + xa.y + xa.z + xa.w + xb.x + xb.y + xb.z + xb.w;
    s_sq  += xa.x*xa.x + xa.y*xa.y + xa.z*xa.z + xa.w*xa.w
           + xb.x*xb.x + xb.y*xb.y + xb.z*xb.z + xb.w*xb.w;
    uint4 wpack = make_uint4(pkbf(xa.x,xa.y), pkbf(xa.z,xa.w),
                             pkbf(xb.x,xb.y), pkbf(xb.z,xb.w));
    *(uint4*)&As[ar][ah] = wpack;
    *(uint4*)&Bs[bc][bh]     = *(const uint4*)(wsrc + k0);
    *(uint4*)&Bs[bc][bh + 8] = *(const uint4*)(wsrc + k0 + 8);
    __syncthreads();
    bf16x8 af[4], bfr[4];
    #pragma unroll
    for (int i = 0; i < 4; i++) {
      af[i]  = *(const bf16x8*)&As[wr * 64 + i * 16 + cl][kq * 8];
      bfr[i] = *(const bf16x8*)&Bs[wc * 64 + i * 16 + cl][kq * 8];
    }
    #pragma unroll
    for (int mi = 0; mi < 4; mi++)
      #pragma unroll
      for (int ni = 0; ni < 4; ni++)
        acc[mi][ni] = __builtin_amdgcn_mfma_f32_16x16x32_bf16(
            af[mi], bfr[ni], acc[mi][ni], 0, 0, 0);
    __syncthreads();
  }

  // row stats: 4 threads/row, combine via xor 1,2
  s_sum += __shfl_xor(s_sum, 1, 64);
  s_sq  += __shfl_xor(s_sq, 1, 64);
  s_sum += __shfl_xor(s_sum, 2, 64);
  s_sq  += __shfl_xor(s_sq, 2, 64);
  if ((tid & 3) == 0) {
    float mean = s_sum * (1.f / 256.f);
    float var = s_sq * (1.f / 256.f) - mean * mean;
    mean_s[ar] = mean;
    rstd_s[ar] = rsqrtf(var + LN_EPS);
  }
  __syncthreads();

  // epilogue: D layout col=lane&15, row=(lane>>4)*4+reg
  int rbase = wr * 64 + kq * 4;
  #pragma unroll
  for (int ni = 0; ni < 4; ni++) {
    int c_loc = wc * 64 + ni * 16 + cl;        // 0..255
    float tj = Tj[c_loc];
    float uj = Uj[c_loc];
    ushort* outp = (c_loc < 128) ? kg : vg;
    int cc = c_loc & 127;
    #pragma unroll
    for (int mi = 0; mi < 4; mi++) {
      #pragma unroll
      for (int j = 0; j < 4; j++) {
        int r = rbase + mi * 16 + j;
        float val = rstd_s[r] * (acc[mi][ni][j] - mean_s[r] * tj) + uj;
        outp[(size_t)(row0 + r) * 128 + cc] = f2bf(val);
      }
    }
  }
}

// ---------------------------------------------------------------------------
// Attention pass (bf16 k/v): block = (b, 128-row chunk). 16-lane row groups:
// lane owns 8 dims (ds_read_b128); 4-stage shfl reduce; softmax over M=7;
// accumulates num[b][m][d], den[b][m]; LDS combine + global atomics.
// ---------------------------------------------------------------------------
__global__ __launch_bounds__(256) void attn_pass(
    const ushort* __restrict__ kg, const ushort* __restrict__ vg,
    const float* __restrict__ qs_g, float* __restrict__ num_g,
    float* __restrict__ den_g) {
  __shared__ ushort kt[32 * 128];
  __shared__ ushort vt[32 * 128];
  __shared__ float nshare[4 * 896];
  __shared__ float dshare[28];
  int tid = threadIdx.x;
  int lane = tid & 63, w = tid >> 6;
  int g = lane >> 4, s16 = lane & 15;     // row-in-group, dim-group
  int b = blockIdx.y;
  int cb = blockIdx.x;                    // 128-row chunk

  // q fragments: 8 dims per lane, all 7 slots
  float qrf[7][8];
  #pragma unroll
  for (int m = 0; m < 7; m++) {
    float4 qa = *(const float4*)&qs_g[b * 896 + m * 128 + s16 * 8];
    float4 qb = *(const float4*)&qs_g[b * 896 + m * 128 + s16 * 8 + 4];
    qrf[m][0]=qa.x; qrf[m][1]=qa.y; qrf[m][2]=qa.z; qrf[m][3]=qa.w;
    qrf[m][4]=qb.x; qrf[m][5]=qb.y; qrf[m][6]=qb.z; qrf[m][7]=qb.w;
  }
  float numr[7][8] = {};
  float denr[7] = {};
  const ushort* kb = kg + ((size_t)b * Nn + cb * 128) * 128;
  const ushort* vb = vg + ((size_t)b * Nn + cb * 128) * 128;

  for (int t = 0; t < 4; t++) {           // 4 tiles of 32 rows
    for (int i = tid; i < 512; i += 256) {
      int r = i >> 4;
      int c8 = (i & 15) * 8;
      *(uint4*)&kt[r * 128 + c8] = *(const uint4*)&kb[(size_t)(t * 32 + r) * 128 + c8];
      *(uint4*)&vt[r * 128 + c8] = *(const uint4*)&vb[(size_t)(t * 32 + r) * 128 + c8];
    }
    __syncthreads();
    #pragma unroll
    for (int batch = 0; batch < 2; batch++) {
      int r = w * 8 + batch * 4 + g;
      uint4 kk = *(uint4*)&kt[r * 128 + s16 * 8];
      float kf[8];
      kf[0]=bf2f((ushort)(kk.x&0xffff)); kf[1]=bf2f((ushort)(kk.x>>16));
      kf[2]=bf2f((ushort)(kk.y&0xffff)); kf[3]=bf2f((ushort)(kk.y>>16));
      kf[4]=bf2f((ushort)(kk.z&0xffff)); kf[5]=bf2f((ushort)(kk.z>>16));
      kf[6]=bf2f((ushort)(kk.w&0xffff)); kf[7]=bf2f((ushort)(kk.w>>16));
      float p[7];
      #pragma unroll
      for (int m = 0; m < 7; m++) {
        float a = 0.f;
        #pragma unroll
        for (int j = 0; j < 8; j++) a += kf[j] * qrf[m][j];
        p[m] = a;
      }
      #pragma unroll
      for (int s = 1; s < 16; s <<= 1)
        #pragma unroll
        for (int m = 0; m < 7; m++) p[m] += __shfl_xor(p[m], s, 64);
      float mx = -1e30f;
      #pragma unroll
      for (int m = 0; m < 7; m++) { p[m] *= SCALE; mx = fmaxf(mx, p[m]); }
      float se = 0.f, e[7];
      #pragma unroll
      for (int m = 0; m < 7; m++) { e[m] = __expf(p[m] - mx); se += e[m]; }
      float inv = 1.f / se;
      uint4 vv = *(uint4*)&vt[r * 128 + s16 * 8];
      float vf[8];
      vf[0]=bf2f((ushort)(vv.x&0xffff)); vf[1]=bf2f((ushort)(vv.x>>16));
      vf[2]=bf2f((ushort)(vv.y&0xffff)); vf[3]=bf2f((ushort)(vv.y>>16));
      vf[4]=bf2f((ushort)(vv.z&0xffff)); vf[5]=bf2f((ushort)(vv.z>>16));
      vf[6]=bf2f((ushort)(vv.w&0xffff)); vf[7]=bf2f((ushort)(vv.w>>16));
      #pragma unroll
      for (int m = 0; m < 7; m++) {
        float a = e[m] * inv + EPS;
        denr[m] += a;
        #pragma unroll
        for (int j = 0; j < 8; j++) numr[m][j] += a * vf[j];
      }
    }
    __syncthreads();
  }

  // reduce across the 4 row-groups (xor 16, 32)
  #pragma unroll
  for (int m = 0; m < 7; m++) {
    #pragma unroll
    for (int j = 0; j < 8; j++) {
      numr[m][j] += __shfl_xor(numr[m][j], 16, 64);
      numr[m][j] += __shfl_xor(numr[m][j], 32, 64);
    }
    denr[m] += __shfl_xor(denr[m], 16, 64);
    denr[m] += __shfl_xor(denr[m], 32, 64);
  }
  if (g == 0) {
    #pragma unroll
    for (int m = 0; m < 7; m++) {
      float4 n0 = make_float4(numr[m][0], numr[m][1], numr[m][2], numr[m][3]);
      float4 n1 = make_float4(numr[m][4], numr[m][5], numr[m][6], numr[m][7]);
      *(float4*)&nshare[w * 896 + m * 128 + s16 * 8]     = n0;
      *(float4*)&nshare[w * 896 + m * 128 + s16 * 8 + 4] = n1;
    }
  }
  if (lane == 0) {
    #pragma unroll
    for (int m = 0; m < 7; m++) dshare[w * 7 + m] = denr[m];
  }
  __syncthreads();
  for (int i = tid; i < 896; i += 256) {
    float s = nshare[i] + nshare[896 + i] + nshare[1792 + i] + nshare[2688 + i];
    atomicAdd(&num_g[b * 896 + i], s);
  }
  if (tid < 7) {
    float s = dshare[tid] + dshare[7 + tid] + dshare[14 + tid] + dshare[21 + tid];
    atomicAdd(&den_g[b * 7 + tid], s);
  }
}

// ---------------------------------------------------------------------------
// GRU cell + residual MLP + q for next iter + zero num/den for next iter.
// One block per (b,m) row of 128.  NOTE: num_g/den_g are read-write here.
// ---------------------------------------------------------------------------
__global__ __launch_bounds__(128) void gru_mlp(
    float* __restrict__ num_g, float* __restrict__ den_g,
    float* __restrict__ slots, const float* __restrict__ wiT,
    const float* __restrict__ whT, const float* __restrict__ gbi,
    const float* __restrict__ gbh, const float* __restrict__ w1T,
    const float* __restrict__ w2T, const float* __restrict__ b1,
    const float* __restrict__ b2, const float* __restrict__ lmw,
    const float* __restrict__ lmb, const float* __restrict__ lsw,
    const float* __restrict__ lsb, const float* __restrict__ WqT,
    float* __restrict__ qs_g) {
  int row = blockIdx.x;             // b*7+m
  int t = threadIdx.x;
  __shared__ float us[128], hs[128], ys[128], hid[256];
  __shared__ float red[4];
  float den = den_g[row];
  float u = num_g[row * 128 + t] / den;
  float h = slots[row * 128 + t];
  us[t] = u;
  hs[t] = h;
  __syncthreads();
  float gr = gbi[t], gz = gbi[128 + t], gn = gbi[256 + t];
  float hr = gbh[t], hz = gbh[128 + t], hn = gbh[256 + t];
  for (int dd = 0; dd < 128; dd++) {
    float uv = us[dd], hv = hs[dd];
    const float* wi = wiT + dd * 384;
    const float* wh = whT + dd * 384;
    gr += uv * wi[t];
    gz += uv * wi[128 + t];
    gn += uv * wi[256 + t];
    hr += hv * wh[t];
    hz += hv * wh[128 + t];
    hn += hv * wh[256 + t];
  }
  float r = 1.f / (1.f + __expf(-(gr + hr)));
  float z = 1.f / (1.f + __expf(-(gz + hz)));
  float n = tanhf(gn + r * hn);
  float sn = (1.f - z) * n + z * h;
  // LN (ln_mlp)
  float sv = sn, sq = sn * sn;
  for (int s = 1; s < 64; s <<= 1) {
    sv += __shfl_xor(sv, s, 64);
    sq += __shfl_xor(sq, s, 64);
  }
  if ((t & 63) == 0) {
    red[(t >> 6) * 2] = sv;
    red[(t >> 6) * 2 + 1] = sq;
  }
  __syncthreads();
  float tot = red[0] + red[2], totq = red[1] + red[3];
  float mean = tot * (1.f / 128.f);
  float var = totq * (1.f / 128.f) - mean * mean;
  float y = (sn - mean) * rsqrtf(var + LN_EPS) * lmw[t] + lmb[t];
  ys[t] = y;
  __syncthreads();
  float h0 = b1[t], h1 = b1[128 + t];
  for (int dd = 0; dd < 128; dd++) {
    float yv = ys[dd];
    h0 += yv * w1T[dd * 256 + t];
    h1 += yv * w1T[dd * 256 + 128 + t];
  }
  hid[t] = fmaxf(h0, 0.f);
  hid[128 + t] = fmaxf(h1, 0.f);
  __syncthreads();
  float o = sn + b2[t];
  for (int j = 0; j < 256; j++) o += hid[j] * w2T[j * 128 + t];
  slots[row * 128 + t] = o;
  // ---- q for next iteration: LN (ln_slot) then @WqT ----
  float sv2 = o, sq2 = o * o;
  for (int s = 1; s < 64; s <<= 1) {
    sv2 += __shfl_xor(sv2, s, 64);
    sq2 += __shfl_xor(sq2, s, 64);
  }
  if ((t & 63) == 0) {
    red[(t >> 6) * 2] = sv2;
    red[(t >> 6) * 2 + 1] = sq2;
  }
  __syncthreads();
  float tot2 = red[0] + red[2], totq2 = red[1] + red[3];
  float mean2 = tot2 * (1.f / 128.f);
  float var2 = totq2 * (1.f / 128.f) - mean2 * mean2;
  float y2 = (o - mean2) * rsqrtf(var2 + LN_EPS) * lsw[t] + lsb[t];
  ys[t] = y2;
  __syncthreads();
  float q = 0.f;
  for (int dd = 0; dd < 128; dd++) q += ys[dd] * WqT[dd * 128 + t];
  qs_g[row * 128 + t] = q;
  num_g[row * 128 + t] = 0.f;
  if (t == 0) den_g[row] = 0.f;
}

// ---------------------------------------------------------------------------
extern "C" void kernel_launch(void* const* d_in, const int* in_sizes, int n_in,
                              void* d_out, int out_size, void* d_ws, size_t ws_size,
                              hipStream_t stream) {
  (void)in_sizes; (void)n_in; (void)out_size; (void)ws_size;
  const float* inputs  = (const float*)d_in[0];
  const float* slots_mu= (const float*)d_in[1];
  const float* ln_in_w = (const float*)d_in[2];
  const float* ln_in_b = (const float*)d_in[3];
  const float* ln_sl_w = (const float*)d_in[4];
  const float* ln_sl_b = (const float*)d_in[5];
  const float* ln_ml_w = (const float*)d_in[6];
  const float* ln_ml_b = (const float*)d_in[7];
  const float* Wq      = (const float*)d_in[8];
  const float* Wk      = (const float*)d_in[9];
  const float* Wv      = (const float*)d_in[10];
  const float* gru_wi  = (const float*)d_in[11];
  const float* gru_wh  = (const float*)d_in[12];
  const float* gru_bi  = (const float*)d_in[13];
  const float* gru_bh  = (const float*)d_in[14];
  const float* mlp_w1  = (const float*)d_in[15];
  const float* mlp_b1  = (const float*)d_in[16];
  const float* mlp_w2  = (const float*)d_in[17];
  const float* mlp_b2  = (const float*)d_in[18];
  float* slots = (float*)d_out;

  char* base = (char*)d_ws;
  size_t o = 0;
  ushort* kg = (ushort*)(base + o); o += (size_t)Bb * Nn * Dd * 2;
  ushort* vg = (ushort*)(base + o); o += (size_t)Bb * Nn * Dd * 2;
  ushort* Wp = (ushort*)(base + o); o += 256 * 256 * 2;
  float* Tj  = (float*)(base + o); o += 256 * 4;
  float* Uj  = (float*)(base + o); o += 256 * 4;
  float* WqT = (float*)(base + o); o += 128 * 128 * 4;
  float* wiT = (float*)(base + o); o += 384 * 128 * 4;
  float* whT = (float*)(base + o); o += 384 * 128 * 4;
  float* w1T = (float*)(base + o); o += 256 * 128 * 4;
  float* w2T = (float*)(base + o); o += 256 * 128 * 4;
  float* num_g = (float*)(base + o); o += (size_t)Bb * Mm * Dd * 4;
  float* den_g = (float*)(base + o); o += (size_t)Bb * Mm * 4;
  float* qs_g  = (float*)(base + o); o += (size_t)Bb * Mm * Dd * 4;

  prep_w2t<<<256, 256, 0, stream>>>(Wk, Wv, ln_in_w, ln_in_b, Wp, Tj, Uj);
  prep_trans<<<704, 256, 0, stream>>>(Wq, gru_wi, gru_wh, mlp_w1, mlp_w2,
                                      WqT, wiT, whT, w1T, w2T);
  q_prep0<<<Bb * Mm, 128, 0, stream>>>(slots_mu, slots, ln_sl_w, ln_sl_b,
                                       WqT, qs_g, num_g, den_g);
  kv_gemm_mfma<<<(Bb * Nn) / 128, 512, 0, stream>>>(inputs, Wp, Tj, Uj, kg, vg);
  for (int it = 0; it < ITERS; it++) {
    attn_pass<<<dim3(Nn / 128, Bb), 256, 0, stream>>>(kg, vg, qs_g, num_g, den_g);
    gru_mlp<<<Bb * Mm, 128, 0, stream>>>(num_g, den_g, slots, wiT, whT,
                                         gru_bi, gru_bh, w1T, w2T,
                                         mlp_b1, mlp_b2, ln_ml_w, ln_ml_b,
                                         ln_sl_w, ln_sl_b, WqT, qs_g);
  }
}

// Round 9
// 433.658 us; speedup vs baseline: 1.0336x; 1.0336x over previous
//
#include <hip/hip_runtime.h>
#include <math.h>

#define Bb 32
#define Nn 4096
#define Cc 256
#define Mm 7
#define Dd 128
#define Hh 256
#define ITERS 3
#define EPS 1e-6f
#define LN_EPS 1e-5f
// SCALE * log2(e): q is pre-scaled so attn works in exp2 domain
#define QSCALE 0.12751743f

typedef __attribute__((ext_vector_type(8))) short bf16x8;
typedef __attribute__((ext_vector_type(4))) float f32x4;

__device__ inline ushort f2bf(float f) {
  uint u = __builtin_bit_cast(uint, f);
  u += 0x7FFF + ((u >> 16) & 1);          // round-to-nearest-even
  return (ushort)(u >> 16);
}
__device__ inline float bf2f(ushort h) {
  uint u = ((uint)h) << 16;
  return __builtin_bit_cast(float, u);
}
__device__ inline uint pkbf(float a, float b) {
  return (uint)f2bf(a) | ((uint)f2bf(b) << 16);
}
__device__ inline float bflo(uint u) {            // low bf16 of a packed uint
  return __builtin_bit_cast(float, u << 16);
}
__device__ inline float bfhi(uint u) {            // high bf16 of a packed uint
  return __builtin_bit_cast(float, u & 0xffff0000u);
}

// ---------------------------------------------------------------------------
// Prep: Wp[j][c] = bf16( ln_in_w[c] * Wkv[j][c] )   (j<128 -> Wk, else Wv)
//       Tj[j] = sum_c lw[c]*W[j][c], Uj[j] = sum_c lb[c]*W[j][c]   (fp32)
// ---------------------------------------------------------------------------
__global__ __launch_bounds__(256) void prep_w2t(
    const float* __restrict__ Wk, const float* __restrict__ Wv,
    const float* __restrict__ lw, const float* __restrict__ lb,
    ushort* __restrict__ Wp, float* __restrict__ Tj, float* __restrict__ Uj) {
  int j = blockIdx.x;     // 0..255 output channel
  int c = threadIdx.x;    // 0..255 input channel
  float wv = (j < Dd) ? Wk[j * Cc + c] : Wv[(j - Dd) * Cc + c];
  float lwc = lw[c], lbc = lb[c];
  float a = lwc * wv, u = lbc * wv;
  Wp[j * 256 + c] = f2bf(a);
  __shared__ float ra[4], ru[4];
  for (int s = 1; s < 64; s <<= 1) {
    a += __shfl_xor(a, s, 64);
    u += __shfl_xor(u, s, 64);
  }
  int lane = c & 63, w = c >> 6;
  if (lane == 0) { ra[w] = a; ru[w] = u; }
  __syncthreads();
  if (c == 0) {
    Tj[j] = ra[0] + ra[1] + ra[2] + ra[3];
    Uj[j] = ru[0] + ru[1] + ru[2] + ru[3];
  }
}

// ---------------------------------------------------------------------------
// Prep: transposes (fp32, coalesced). WqT is pre-scaled by QSCALE so the
// attention logits come out in log2 domain.
// ---------------------------------------------------------------------------
__global__ __launch_bounds__(256) void prep_trans(
    const float* __restrict__ Wq, const float* __restrict__ wi,
    const float* __restrict__ wh, const float* __restrict__ w1,
    const float* __restrict__ w2, float* __restrict__ WqT,
    float* __restrict__ wiT, float* __restrict__ whT,
    float* __restrict__ w1T, float* __restrict__ w2T) {
  int i = blockIdx.x * 256 + threadIdx.x;
  if (i < 16384) {                        // WqT[dd][d] = Wq[d][dd] * QSCALE
    int dd = i >> 7, d = i & 127;
    WqT[i] = Wq[d * 128 + dd] * QSCALE;
  } else if (i < 65536) {                 // wiT[dd][j] = wi[j][dd]
    int i2 = i - 16384;
    int dd = i2 / 384, j = i2 % 384;
    wiT[i2] = wi[j * 128 + dd];
  } else if (i < 114688) {                // whT
    int i2 = i - 65536;
    int dd = i2 / 384, j = i2 % 384;
    whT[i2] = wh[j * 128 + dd];
  } else if (i < 147456) {                // w1T[dd][j] = w1[j][dd]
    int i2 = i - 114688;
    int dd = i2 >> 8, j = i2 & 255;
    w1T[i2] = w1[j * 128 + dd];
  } else if (i < 180224) {                // w2T[j][d] = w2[d][j]
    int i2 = i - 147456;
    int j = i2 >> 7, d = i2 & 127;
    w2T[i2] = w2[d * 256 + j];
  }
}

// ---------------------------------------------------------------------------
// q for iteration 0 + slots init + zero num/den. Block = (b*7+m), 128 thr.
// ---------------------------------------------------------------------------
__global__ __launch_bounds__(128) void q_prep0(
    const float* __restrict__ slots_mu, float* __restrict__ slots,
    const float* __restrict__ lsw, const float* __restrict__ lsb,
    const float* __restrict__ WqT, float* __restrict__ qs_g,
    float* __restrict__ num_g, float* __restrict__ den_g) {
  int row = blockIdx.x;
  int t = threadIdx.x;
  __shared__ float ys[128];
  __shared__ float red[4];
  float v = slots_mu[row * 128 + t];
  slots[row * 128 + t] = v;
  float sv = v, sq = v * v;
  for (int s = 1; s < 64; s <<= 1) {
    sv += __shfl_xor(sv, s, 64);
    sq += __shfl_xor(sq, s, 64);
  }
  if ((t & 63) == 0) {
    red[(t >> 6) * 2] = sv;
    red[(t >> 6) * 2 + 1] = sq;
  }
  __syncthreads();
  float tot = red[0] + red[2], totq = red[1] + red[3];
  float mean = tot * (1.f / 128.f);
  float var = totq * (1.f / 128.f) - mean * mean;
  ys[t] = (v - mean) * rsqrtf(var + LN_EPS) * lsw[t] + lsb[t];
  __syncthreads();
  float q = 0.f;
  for (int dd = 0; dd < 128; dd++) q += ys[dd] * WqT[dd * 128 + t];
  qs_g[row * 128 + t] = q;
  num_g[row * 128 + t] = 0.f;
  if (t == 0) den_g[row] = 0.f;
}

// ---------------------------------------------------------------------------
// KV projection, bf16 MFMA: out[row][j] = rstd*(x.W'_j - mean*Tj) + Uj
// 131072 x 256(K) x 256(N), BOTH k and v per block (x read once).
// 512 threads = 8 waves, wave grid 2x4, each 64x64 output.
// Register prefetch: tile k+1 loads issued before tile k's MFMA phase.
// ---------------------------------------------------------------------------
__global__ __launch_bounds__(512) void kv_gemm_mfma(
    const float* __restrict__ x, const ushort* __restrict__ Wp,
    const float* __restrict__ Tj, const float* __restrict__ Uj,
    ushort* __restrict__ kg, ushort* __restrict__ vg) {
  __shared__ ushort As[128][40];   // [row][k] bf16, 80B stride
  __shared__ ushort Bs[256][40];   // [col][k] bf16
  __shared__ float mean_s[128], rstd_s[128];
  int tid = threadIdx.x;
  int lane = tid & 63, w = tid >> 6;      // 8 waves
  int wr = w >> 2, wc = w & 3;            // 2x4 wave grid
  int cl = lane & 15, kq = lane >> 4;
  int row0 = blockIdx.x * 128;

  int ar = tid >> 2;                      // A staging: row 0..127
  int ah = (tid & 3) * 8;                 // 8 floats per thread
  int bc = tid >> 1;                      // B staging: col 0..255
  int bh = (tid & 1) * 16;                // 16 bf16 per thread
  const float*  xsrc = x  + (size_t)(row0 + ar) * 256 + ah;
  const ushort* wsrc = Wp + (size_t)bc * 256 + bh;

  float s_sum = 0.f, s_sq = 0.f;
  f32x4 acc[4][4] = {};

  // prologue: tile 0 into registers
  float4 xa = *(const float4*)(xsrc);
  float4 xb = *(const float4*)(xsrc + 4);
  uint4 wb0 = *(const uint4*)(wsrc);
  uint4 wb1 = *(const uint4*)(wsrc + 8);

  for (int k0 = 0; k0 < 256; k0 += 32) {
    // consume current regs: stats + pack + LDS write
    s_sum += xa.x + xa.y + xa.z + xa.w + xb.x + xb.y + xb.z + xb.w;
    s_sq  += xa.x*xa.x + xa.y*xa.y + xa.z*xa.z + xa.w*xa.w
           + xb.x*xb.x + xb.y*xb.y + xb.z*xb.z + xb.w*xb.w;
    uint4 wpack = make_uint4(pkbf(xa.x,xa.y), pkbf(xa.z,xa.w),
                             pkbf(xb.x,xb.y), pkbf(xb.z,xb.w));
    *(uint4*)&As[ar][ah] = wpack;
    *(uint4*)&Bs[bc][bh]     = wb0;
    *(uint4*)&Bs[bc][bh + 8] = wb1;
    // issue next tile's loads (land during MFMA phase)
    if (k0 < 224) {
      xa  = *(const float4*)(xsrc + k0 + 32);
      xb  = *(const float4*)(xsrc + k0 + 36);
      wb0 = *(const uint4*)(wsrc + k0 + 32);
      wb1 = *(const uint4*)(wsrc + k0 + 40);
    }
    __syncthreads();
    bf16x8 af[4], bfr[4];
    #pragma unroll
    for (int i = 0; i < 4; i++) {
      af[i]  = *(const bf16x8*)&As[wr * 64 + i * 16 + cl][kq * 8];
      bfr[i] = *(const bf16x8*)&Bs[wc * 64 + i * 16 + cl][kq * 8];
    }
    #pragma unroll
    for (int mi = 0; mi < 4; mi++)
      #pragma unroll
      for (int ni = 0; ni < 4; ni++)
        acc[mi][ni] = __builtin_amdgcn_mfma_f32_16x16x32_bf16(
            af[mi], bfr[ni], acc[mi][ni], 0, 0, 0);
    __syncthreads();
  }

  // row stats: 4 threads/row, combine via xor 1,2
  s_sum += __shfl_xor(s_sum, 1, 64);
  s_sq  += __shfl_xor(s_sq, 1, 64);
  s_sum += __shfl_xor(s_sum, 2, 64);
  s_sq  += __shfl_xor(s_sq, 2, 64);
  if ((tid & 3) == 0) {
    float mean = s_sum * (1.f / 256.f);
    float var = s_sq * (1.f / 256.f) - mean * mean;
    mean_s[ar] = mean;
    rstd_s[ar] = rsqrtf(var + LN_EPS);
  }
  __syncthreads();

  // epilogue: D layout col=lane&15, row=(lane>>4)*4+reg
  int rbase = wr * 64 + kq * 4;
  #pragma unroll
  for (int ni = 0; ni < 4; ni++) {
    int c_loc = wc * 64 + ni * 16 + cl;        // 0..255
    float tj = Tj[c_loc];
    float uj = Uj[c_loc];
    ushort* outp = (c_loc < 128) ? kg : vg;
    int cc = c_loc & 127;
    #pragma unroll
    for (int mi = 0; mi < 4; mi++) {
      #pragma unroll
      for (int j = 0; j < 4; j++) {
        int r = rbase + mi * 16 + j;
        float val = rstd_s[r] * (acc[mi][ni][j] - mean_s[r] * tj) + uj;
        outp[(size_t)(row0 + r) * 128 + cc] = f2bf(val);
      }
    }
  }
}

// ---------------------------------------------------------------------------
// Attention pass (bf16 k/v), barrier-free streaming. Block = (chunk, b),
// 4 waves; each WAVE independently owns 32 rows (8 iterations x 4 rows).
// No LDS staging (zero data reuse); depth-2 register ping-pong prefetch.
// 16-lane row groups: lane owns 8 dims; 4-stage shfl reduce; exp2-domain
// softmax (q pre-scaled by SCALE*log2e); accumulates num/den; LDS combine
// across the 4 waves; global atomics.
// ---------------------------------------------------------------------------
__global__ __launch_bounds__(256) void attn_pass(
    const ushort* __restrict__ kg, const ushort* __restrict__ vg,
    const float* __restrict__ qs_g, float* __restrict__ num_g,
    float* __restrict__ den_g) {
  __shared__ float nshare[4 * 896];
  __shared__ float dshare[28];
  int tid = threadIdx.x;
  int lane = tid & 63, w = tid >> 6;
  int g = lane >> 4, s16 = lane & 15;     // row-in-batch, dim-group
  int b = blockIdx.y;
  int cb = blockIdx.x;                    // 32 chunks of 128 rows

  // q fragments: 8 dims per lane, all 7 slots (already in log2 scale)
  float qrf[7][8];
  #pragma unroll
  for (int m = 0; m < 7; m++) {
    float4 qa = *(const float4*)&qs_g[b * 896 + m * 128 + s16 * 8];
    float4 qb = *(const float4*)&qs_g[b * 896 + m * 128 + s16 * 8 + 4];
    qrf[m][0]=qa.x; qrf[m][1]=qa.y; qrf[m][2]=qa.z; qrf[m][3]=qa.w;
    qrf[m][4]=qb.x; qrf[m][5]=qb.y; qrf[m][6]=qb.z; qrf[m][7]=qb.w;
  }
  float numr[7][8] = {};
  float denr[7] = {};

  size_t base = ((size_t)b * Nn + (size_t)cb * 128 + w * 32) * 128;
  const ushort* kp = kg + base;
  const ushort* vp = vg + base;
  int loff = g * 128 + s16 * 8;           // lane's slot within a 4-row batch

  uint4 kb0 = *(const uint4*)&kp[loff];
  uint4 vb0 = *(const uint4*)&vp[loff];
  uint4 kb1, vb1;

  #pragma unroll
  for (int it = 0; it < 8; it++) {
    uint4 kk = (it & 1) ? kb1 : kb0;
    uint4 vv = (it & 1) ? vb1 : vb0;
    if (it < 7) {
      int noff = (it + 1) * 512 + loff;
      if (it & 1) { kb0 = *(const uint4*)&kp[noff]; vb0 = *(const uint4*)&vp[noff]; }
      else        { kb1 = *(const uint4*)&kp[noff]; vb1 = *(const uint4*)&vp[noff]; }
    }
    float kf[8];
    kf[0]=bflo(kk.x); kf[1]=bfhi(kk.x); kf[2]=bflo(kk.y); kf[3]=bfhi(kk.y);
    kf[4]=bflo(kk.z); kf[5]=bfhi(kk.z); kf[6]=bflo(kk.w); kf[7]=bfhi(kk.w);
    float p[7];
    #pragma unroll
    for (int m = 0; m < 7; m++) {
      float a = 0.f;
      #pragma unroll
      for (int j = 0; j < 8; j++) a += kf[j] * qrf[m][j];
      p[m] = a;
    }
    #pragma unroll
    for (int s = 1; s < 16; s <<= 1)
      #pragma unroll
      for (int m = 0; m < 7; m++) p[m] += __shfl_xor(p[m], s, 64);
    float e[7], se = 0.f;
    #pragma unroll
    for (int m = 0; m < 7; m++) { e[m] = exp2f(p[m]); se += e[m]; }
    float inv = __builtin_amdgcn_rcpf(se);  // error cancels in num/den ratio
    float vf[8];
    vf[0]=bflo(vv.x); vf[1]=bfhi(vv.x); vf[2]=bflo(vv.y); vf[3]=bfhi(vv.y);
    vf[4]=bflo(vv.z); vf[5]=bfhi(vv.z); vf[6]=bflo(vv.w); vf[7]=bfhi(vv.w);
    #pragma unroll
    for (int m = 0; m < 7; m++) {
      float a = e[m] * inv + EPS;
      denr[m] += a;
      #pragma unroll
      for (int j = 0; j < 8; j++) numr[m][j] += a * vf[j];
    }
  }

  // fold the 4 row-groups (lanes with same s16, different g)
  #pragma unroll
  for (int m = 0; m < 7; m++) {
    #pragma unroll
    for (int j = 0; j < 8; j++) {
      numr[m][j] += __shfl_xor(numr[m][j], 16, 64);
      numr[m][j] += __shfl_xor(numr[m][j], 32, 64);
    }
    denr[m] += __shfl_xor(denr[m], 16, 64);
    denr[m] += __shfl_xor(denr[m], 32, 64);
  }
  if (g == 0) {
    #pragma unroll
    for (int m = 0; m < 7; m++) {
      float4 n0 = make_float4(numr[m][0], numr[m][1], numr[m][2], numr[m][3]);
      float4 n1 = make_float4(numr[m][4], numr[m][5], numr[m][6], numr[m][7]);
      *(float4*)&nshare[w * 896 + m * 128 + s16 * 8]     = n0;
      *(float4*)&nshare[w * 896 + m * 128 + s16 * 8 + 4] = n1;
    }
  }
  if (lane == 0) {
    #pragma unroll
    for (int m = 0; m < 7; m++) dshare[w * 7 + m] = denr[m];
  }
  __syncthreads();
  for (int i = tid; i < 896; i += 256) {
    float s = nshare[i] + nshare[896 + i] + nshare[1792 + i] + nshare[2688 + i];
    atomicAdd(&num_g[b * 896 + i], s);
  }
  if (tid < 7) {
    float s = dshare[tid] + dshare[7 + tid] + dshare[14 + tid] + dshare[21 + tid];
    atomicAdd(&den_g[b * 7 + tid], s);
  }
}

// ---------------------------------------------------------------------------
// GRU cell + residual MLP + q for next iter + zero num/den for next iter.
// One block per (b,m) row of 128.  num_g/den_g are read-write here.
// ---------------------------------------------------------------------------
__global__ __launch_bounds__(128) void gru_mlp(
    float* __restrict__ num_g, float* __restrict__ den_g,
    float* __restrict__ slots, const float* __restrict__ wiT,
    const float* __restrict__ whT, const float* __restrict__ gbi,
    const float* __restrict__ gbh, const float* __restrict__ w1T,
    const float* __restrict__ w2T, const float* __restrict__ b1,
    const float* __restrict__ b2, const float* __restrict__ lmw,
    const float* __restrict__ lmb, const float* __restrict__ lsw,
    const float* __restrict__ lsb, const float* __restrict__ WqT,
    float* __restrict__ qs_g) {
  int row = blockIdx.x;             // b*7+m
  int t = threadIdx.x;
  __shared__ float us[128], hs[128], ys[128], hid[256];
  __shared__ float red[4];
  float den = den_g[row];
  float u = num_g[row * 128 + t] / den;
  float h = slots[row * 128 + t];
  us[t] = u;
  hs[t] = h;
  __syncthreads();
  float gr = gbi[t], gz = gbi[128 + t], gn = gbi[256 + t];
  float hr = gbh[t], hz = gbh[128 + t], hn = gbh[256 + t];
  for (int dd = 0; dd < 128; dd++) {
    float uv = us[dd], hv = hs[dd];
    const float* wi = wiT + dd * 384;
    const float* wh = whT + dd * 384;
    gr += uv * wi[t];
    gz += uv * wi[128 + t];
    gn += uv * wi[256 + t];
    hr += hv * wh[t];
    hz += hv * wh[128 + t];
    hn += hv * wh[256 + t];
  }
  float r = 1.f / (1.f + __expf(-(gr + hr)));
  float z = 1.f / (1.f + __expf(-(gz + hz)));
  float n = tanhf(gn + r * hn);
  float sn = (1.f - z) * n + z * h;
  // LN (ln_mlp)
  float sv = sn, sq = sn * sn;
  for (int s = 1; s < 64; s <<= 1) {
    sv += __shfl_xor(sv, s, 64);
    sq += __shfl_xor(sq, s, 64);
  }
  if ((t & 63) == 0) {
    red[(t >> 6) * 2] = sv;
    red[(t >> 6) * 2 + 1] = sq;
  }
  __syncthreads();
  float tot = red[0] + red[2], totq = red[1] + red[3];
  float mean = tot * (1.f / 128.f);
  float var = totq * (1.f / 128.f) - mean * mean;
  float y = (sn - mean) * rsqrtf(var + LN_EPS) * lmw[t] + lmb[t];
  ys[t] = y;
  __syncthreads();
  float h0 = b1[t], h1 = b1[128 + t];
  for (int dd = 0; dd < 128; dd++) {
    float yv = ys[dd];
    h0 += yv * w1T[dd * 256 + t];
    h1 += yv * w1T[dd * 256 + 128 + t];
  }
  hid[t] = fmaxf(h0, 0.f);
  hid[128 + t] = fmaxf(h1, 0.f);
  __syncthreads();
  float o = sn + b2[t];
  for (int j = 0; j < 256; j++) o += hid[j] * w2T[j * 128 + t];
  slots[row * 128 + t] = o;
  // ---- q for next iteration: LN (ln_slot) then @WqT (pre-scaled) ----
  float sv2 = o, sq2 = o * o;
  for (int s = 1; s < 64; s <<= 1) {
    sv2 += __shfl_xor(sv2, s, 64);
    sq2 += __shfl_xor(sq2, s, 64);
  }
  if ((t & 63) == 0) {
    red[(t >> 6) * 2] = sv2;
    red[(t >> 6) * 2 + 1] = sq2;
  }
  __syncthreads();
  float tot2 = red[0] + red[2], totq2 = red[1] + red[3];
  float mean2 = tot2 * (1.f / 128.f);
  float var2 = totq2 * (1.f / 128.f) - mean2 * mean2;
  float y2 = (o - mean2) * rsqrtf(var2 + LN_EPS) * lsw[t] + lsb[t];
  ys[t] = y2;
  __syncthreads();
  float q = 0.f;
  for (int dd = 0; dd < 128; dd++) q += ys[dd] * WqT[dd * 128 + t];
  qs_g[row * 128 + t] = q;
  num_g[row * 128 + t] = 0.f;
  if (t == 0) den_g[row] = 0.f;
}

// ---------------------------------------------------------------------------
extern "C" void kernel_launch(void* const* d_in, const int* in_sizes, int n_in,
                              void* d_out, int out_size, void* d_ws, size_t ws_size,
                              hipStream_t stream) {
  (void)in_sizes; (void)n_in; (void)out_size; (void)ws_size;
  const float* inputs  = (const float*)d_in[0];
  const float* slots_mu= (const float*)d_in[1];
  const float* ln_in_w = (const float*)d_in[2];
  const float* ln_in_b = (const float*)d_in[3];
  const float* ln_sl_w = (const float*)d_in[4];
  const float* ln_sl_b = (const float*)d_in[5];
  const float* ln_ml_w = (const float*)d_in[6];
  const float* ln_ml_b = (const float*)d_in[7];
  const float* Wq      = (const float*)d_in[8];
  const float* Wk      = (const float*)d_in[9];
  const float* Wv      = (const float*)d_in[10];
  const float* gru_wi  = (const float*)d_in[11];
  const float* gru_wh  = (const float*)d_in[12];
  const float* gru_bi  = (const float*)d_in[13];
  const float* gru_bh  = (const float*)d_in[14];
  const float* mlp_w1  = (const float*)d_in[15];
  const float* mlp_b1  = (const float*)d_in[16];
  const float* mlp_w2  = (const float*)d_in[17];
  const float* mlp_b2  = (const float*)d_in[18];
  float* slots = (float*)d_out;

  char* base = (char*)d_ws;
  size_t o = 0;
  ushort* kg = (ushort*)(base + o); o += (size_t)Bb * Nn * Dd * 2;
  ushort* vg = (ushort*)(base + o); o += (size_t)Bb * Nn * Dd * 2;
  ushort* Wp = (ushort*)(base + o); o += 256 * 256 * 2;
  float* Tj  = (float*)(base + o); o += 256 * 4;
  float* Uj  = (float*)(base + o); o += 256 * 4;
  float* WqT = (float*)(base + o); o += 128 * 128 * 4;
  float* wiT = (float*)(base + o); o += 384 * 128 * 4;
  float* whT = (float*)(base + o); o += 384 * 128 * 4;
  float* w1T = (float*)(base + o); o += 256 * 128 * 4;
  float* w2T = (float*)(base + o); o += 256 * 128 * 4;
  float* num_g = (float*)(base + o); o += (size_t)Bb * Mm * Dd * 4;
  float* den_g = (float*)(base + o); o += (size_t)Bb * Mm * 4;
  float* qs_g  = (float*)(base + o); o += (size_t)Bb * Mm * Dd * 4;

  prep_w2t<<<256, 256, 0, stream>>>(Wk, Wv, ln_in_w, ln_in_b, Wp, Tj, Uj);
  prep_trans<<<704, 256, 0, stream>>>(Wq, gru_wi, gru_wh, mlp_w1, mlp_w2,
                                      WqT, wiT, whT, w1T, w2T);
  q_prep0<<<Bb * Mm, 128, 0, stream>>>(slots_mu, slots, ln_sl_w, ln_sl_b,
                                       WqT, qs_g, num_g, den_g);
  kv_gemm_mfma<<<(Bb * Nn) / 128, 512, 0, stream>>>(inputs, Wp, Tj, Uj, kg, vg);
  for (int it = 0; it < ITERS; it++) {
    attn_pass<<<dim3(Nn / 128, Bb), 256, 0, stream>>>(kg, vg, qs_g, num_g, den_g);
    gru_mlp<<<Bb * Mm, 128, 0, stream>>>(num_g, den_g, slots, wiT, whT,
                                         gru_bi, gru_bh, w1T, w2T,
                                         mlp_b1, mlp_b2, ln_ml_w, ln_ml_b,
                                         ln_sl_w, ln_sl_b, WqT, qs_g);
  }
}